// Round 10
// baseline (6692.272 us; speedup 1.0000x reference)
//
#include <hip/hip_runtime.h>
#include <stdint.h>

#define B_ 64
#define T_ 512
#define D_ 1024
#define U_ 1024
#define G4_ 4096
#define M_ (B_ * T_)   // 32768
#define SLOT 131072    // u16 per h slot: 2 dirs * 64 b * 1024 u

typedef unsigned short u16;
typedef float f32x4 __attribute__((ext_vector_type(4)));
typedef _Float16 f16x8 __attribute__((ext_vector_type(8)));
typedef unsigned short u16x4 __attribute__((ext_vector_type(4)));

__device__ __forceinline__ u16 f2h(float f) {
  union { _Float16 h; u16 u; } v; v.h = (_Float16)f; return v.u;
}
__device__ __forceinline__ float sigm(float x) { return 1.f / (1.f + __expf(-x)); }
__device__ __forceinline__ float tanhf_(float x) {
  x = fminf(12.f, fmaxf(-12.f, x));
  float e = __expf(2.f * x);
  return (e - 1.f) / (e + 1.f);
}

__device__ __forceinline__ void glds16(const void* g, void* l) {
  __builtin_amdgcn_global_load_lds(
      (const __attribute__((address_space(1))) uint32_t*)g,
      (__attribute__((address_space(3))) uint32_t*)l, 16, 0, 0);
}

#define MFMA_(a, b, c) __builtin_amdgcn_mfma_f32_16x16x32_f16(a, b, c, 0, 0, 0)
#define BAR_LGKM() asm volatile("s_waitcnt lgkmcnt(0)\n\ts_barrier" ::: "memory")

// ---------------- prep kernels ----------------

__global__ __launch_bounds__(256) void cast_x_kernel(const float* __restrict__ x,
                                                     u16* __restrict__ xb) {
  const long n = (long)M_ * D_ / 4;
  for (long i = (long)blockIdx.x * blockDim.x + threadIdx.x; i < n;
       i += (long)gridDim.x * blockDim.x) {
    f32x4 v = ((const f32x4*)x)[i];
    u16x4 r;
#pragma unroll
    for (int j = 0; j < 4; ++j) r[j] = f2h(v[j]);
    ((u16x4*)xb)[i] = r;
  }
}

// 8-unit gate-interleaved packing: p = ub*32 + g*8 + ui (ub in [0,128))
//  <-> original col = g*1024 + ub*8 + ui.  wT[d][p][k], k-contiguous fp16.
__global__ __launch_bounds__(256) void pack_w_kernel(const float* __restrict__ Wf,
                                                     const float* __restrict__ Wb,
                                                     u16* __restrict__ wxT,
                                                     u16* __restrict__ whT) {
  const int idx = blockIdx.x * 256 + threadIdx.x;
  const int p = idx & 4095;
  const int kc = (idx >> 12) & 63;
  const int part = (idx >> 18) & 1;   // 0 = x rows, 1 = h rows
  const int d = (idx >> 19) & 1;
  const float* W = d ? Wb : Wf;
  const int orig = ((p >> 3) & 3) * 1024 + ((p >> 5) << 3) + (p & 7);
  u16* dst = (part ? whT : wxT) + ((long)d * G4_ + p) * 1024 + kc * 16;
  const float* src = W + ((long)(part * 1024 + kc * 16)) * G4_ + orig;
#pragma unroll
  for (int j = 0; j < 16; ++j) dst[j] = f2h(src[(long)j * G4_]);
}

// ---------------- persistent recurrent kernel v6: data-poll + fused x ------
// 256 blocks (1/CU): bx -> d = bx&1, ub = bx>>1 in [0,128); 8 units/block.
// 512 threads = 8 waves: wm = wid&3 (16 batch rows each), kh = wid>>2 (K half).
// LDS: Wx 64K | Wh 64K fragment-linear (part,kh,ni,kk -> 1KB blocks), zbuf.
// Per step: issue h-loads (sc0 sc1, versioned poisoned slot - the loads ARE
// the sync: retry while any dword == 0xFFFFFFFF) + x-loads (cached, immutable)
// -> x MFMAs -> h MFMAs -> zbuf K-combine -> gates (bias in regs) -> dword
// h store sc0 sc1 to slot s+1 (write-once; no ack, no flag) -> out store.
#define ZLD2 33
__global__ __launch_bounds__(512) void lstm_persist_dp(
    const u16* __restrict__ whT, const u16* __restrict__ wxT,
    const u16* __restrict__ xbf,
    const float* __restrict__ bF, const float* __restrict__ bB,
    u16* __restrict__ hst, float* __restrict__ out) {
  __shared__ __align__(16) char smem[131072 + ZLD2 * 64 * 4];
  float* zbuf = (float*)(smem + 131072);
  const int tid = threadIdx.x, lane = tid & 63, wid = tid >> 6;
  const int bx = blockIdx.x, d = bx & 1, ub = bx >> 1;
  const int wm = wid & 3, kh = wid >> 2, rA = lane & 15, kq = lane >> 4;

  // ---- stage W once: 128 fragments of 1KB; frag f = part*64+(fkh*2+ni)*16+kk
  {
    const long colbase = ((long)d * G4_ + ub * 32) * 1024;
#pragma unroll
    for (int q = 0; q < 16; ++q) {
      const int f = wid * 16 + q;
      const int part = f >> 6, r = f & 63;
      const int fkh = (r >> 5) & 1, ni = (r >> 4) & 1, kk = r & 15;
      const u16* wsrc = (part ? whT : wxT) + colbase +
                        (long)(ni * 16 + (lane & 15)) * 1024 +
                        fkh * 512 + kk * 32 + kq * 8;
      glds16(wsrc, smem + f * 1024);
    }
  }
  asm volatile("s_waitcnt vmcnt(0)" ::: "memory");
  __syncthreads();

  // ---- gate-thread state (tid < 256): b = tid>>2, unit pair up = tid&3 ----
  const int b_g = tid >> 2, up_g = tid & 3;
  const int u_g = ub * 8 + up_g * 2;
  float bias_[4][2];
  if (tid < 256) {
    const float* bias = d ? bB : bF;
#pragma unroll
    for (int g = 0; g < 4; ++g) {
      bias_[g][0] = bias[g * 1024 + u_g];
      bias_[g][1] = bias[g * 1024 + u_g + 1];
    }
  }
  float creg0 = 0.f, creg1 = 0.f;

  for (int s = 0; s < T_; ++s) {
    const int t = d ? (T_ - 1 - s) : s;

    // ---- issue h-poll loads (LLC-direct) + x loads (cached) ----
    const u16* hr = hst + (long)s * SLOT + (long)d * 65536;
    const char* ah_base =
        (const char*)(hr + (long)(wm * 16 + rA) * 1024) + kh * 1024 + kq * 16;
    const char* ax_base =
        (const char*)(xbf + ((long)(wm * 16 + rA) * T_ + t) * 1024 +
                      kh * 512 + kq * 8);
    f16x8 ah[16], ax[16];
#define AH(i)                                                           \
  asm volatile("global_load_dwordx4 %0, %1, off offset:%2 sc0 sc1"     \
               : "=v"(ah[i]) : "v"(ah_base), "n"(i * 64) : "memory")
#define AX(i)                                                           \
  asm volatile("global_load_dwordx4 %0, %1, off offset:%2"             \
               : "=v"(ax[i]) : "v"(ax_base), "n"(i * 64) : "memory")
    AH(0); AH(1); AH(2); AH(3); AH(4); AH(5); AH(6); AH(7);
    AH(8); AH(9); AH(10); AH(11); AH(12); AH(13); AH(14); AH(15);
    AX(0); AX(1); AX(2); AX(3); AX(4); AX(5); AX(6); AX(7);
    AX(8); AX(9); AX(10); AX(11); AX(12); AX(13); AX(14); AX(15);
#undef AX
    asm volatile("s_waitcnt vmcnt(0)" ::: "memory");
    __builtin_amdgcn_sched_barrier(0);  // rule #18

    // ---- poison poll: retry h loads until no 0xFFFFFFFF dword ----
    {
      int it = 0;
      while (true) {
        int bad = 0;
#pragma unroll
        for (int i = 0; i < 16; ++i) {
          union { f16x8 f; uint32_t u[4]; } c; c.f = ah[i];
          bad |= (c.u[0] == 0xFFFFFFFFu) | (c.u[1] == 0xFFFFFFFFu) |
                 (c.u[2] == 0xFFFFFFFFu) | (c.u[3] == 0xFFFFFFFFu);
        }
        if (!__any(bad)) break;
        if (++it > (1 << 16)) break;  // bailout: no hang
        AH(0); AH(1); AH(2); AH(3); AH(4); AH(5); AH(6); AH(7);
        AH(8); AH(9); AH(10); AH(11); AH(12); AH(13); AH(14); AH(15);
        asm volatile("s_waitcnt vmcnt(0)" ::: "memory");
        __builtin_amdgcn_sched_barrier(0);
      }
    }
#undef AH

    // ---- MFMA: x part (frags part=0) then h part (part=1) ----
    f32x4 acc[2];
#pragma unroll
    for (int ni = 0; ni < 2; ++ni)
#pragma unroll
      for (int v = 0; v < 4; ++v) acc[ni][v] = 0.f;
    const char* fb = smem + (long)(kh * 2) * 16384 + (lane << 4);
#pragma unroll
    for (int kk = 0; kk < 16; ++kk)
#pragma unroll
      for (int ni = 0; ni < 2; ++ni)
        acc[ni] = MFMA_(ax[kk], *(const f16x8*)(fb + (ni * 16 + kk) * 1024), acc[ni]);
    const char* fbh = fb + 65536;
#pragma unroll
    for (int kk = 0; kk < 16; ++kk)
#pragma unroll
      for (int ni = 0; ni < 2; ++ni)
        acc[ni] = MFMA_(ah[kk], *(const f16x8*)(fbh + (ni * 16 + kk) * 1024), acc[ni]);

    // ---- K-combine: kh1 writes, kh0 adds ----
    if (kh == 1) {
#pragma unroll
      for (int ni = 0; ni < 2; ++ni)
#pragma unroll
        for (int v = 0; v < 4; ++v)
          zbuf[(wm * 16 + kq * 4 + v) * ZLD2 + ni * 16 + rA] = acc[ni][v];
    }
    BAR_LGKM();  // B2
    if (kh == 0) {
#pragma unroll
      for (int ni = 0; ni < 2; ++ni)
#pragma unroll
        for (int v = 0; v < 4; ++v) {
          const int ix = (wm * 16 + kq * 4 + v) * ZLD2 + ni * 16 + rA;
          zbuf[ix] += acc[ni][v];
        }
    }
    BAR_LGKM();  // B3

    // ---- gates (tid<256): z cols c = g*8 + up*2; dword h store, no ack ----
    if (tid < 256) {
      const float* zb = zbuf + b_g * ZLD2 + up_g * 2;
      const float zi0 = zb[0]  + bias_[0][0], zi1 = zb[1]  + bias_[0][1];
      const float zf0 = zb[8]  + bias_[1][0], zf1 = zb[9]  + bias_[1][1];
      const float zo0 = zb[16] + bias_[2][0], zo1 = zb[17] + bias_[2][1];
      const float zg0 = zb[24] + bias_[3][0], zg1 = zb[25] + bias_[3][1];
      const float cn0 = sigm(zf0) * creg0 + sigm(zi0) * tanhf_(zg0);
      const float cn1 = sigm(zf1) * creg1 + sigm(zi1) * tanhf_(zg1);
      const float hn0 = sigm(zo0) * tanhf_(cn0);
      const float hn1 = sigm(zo1) * tanhf_(cn1);
      creg0 = cn0; creg1 = cn1;

      u16* hw = hst + (long)(s + 1) * SLOT + (long)d * 65536;
      const uint32_t hv = (uint32_t)f2h(hn0) | ((uint32_t)f2h(hn1) << 16);
      u16* hp = hw + (long)b_g * 1024 + u_g;
      asm volatile("global_store_dword %0, %1, off sc0 sc1"
                   :: "v"(hp), "v"(hv) : "memory");
      float2 o2; o2.x = hn0; o2.y = hn1;
      *(float2*)(out + ((long)b_g * T_ + t) * 2048 + d * 1024 + u_g) = o2;
    }
    BAR_LGKM();  // B4: zbuf WAR for next step
  }
}

// ---------------- host launch ----------------

extern "C" void kernel_launch(void* const* d_in, const int* in_sizes, int n_in,
                              void* d_out, int out_size, void* d_ws, size_t ws_size,
                              hipStream_t stream) {
  const float* x = (const float*)d_in[0];
  const float* Wf = (const float*)d_in[1];
  const float* bfp = (const float*)d_in[2];
  const float* Wb = (const float*)d_in[3];
  const float* bbp = (const float*)d_in[4];
  float* out = (float*)d_out;
  char* ws = (char*)d_ws;

  size_t off = 0;
  auto alloc = [&](size_t bytes) {
    char* p = ws + off;
    off = (off + bytes + 255) & ~(size_t)255;
    return p;
  };
  u16* xbf = (u16*)alloc((size_t)M_ * D_ * 2);             // 64 MB
  u16* wxT = (u16*)alloc((size_t)2 * G4_ * 1024 * 2);      // 16 MB
  u16* whT = (u16*)alloc((size_t)2 * G4_ * 1024 * 2);      // 16 MB
  u16* hst = (u16*)alloc((size_t)(T_ + 1) * SLOT * 2);     // 134.5 MB versioned h
  // total ~231 MB — rounds 4-9 prove ws >= ~610 MB, so this always fits.

  // slot 0 = zeros (initial h); slots 1..T poisoned 0xFF (write-once versioning)
  hipMemsetAsync(hst, 0, (size_t)SLOT * 2, stream);
  hipMemsetAsync(hst + SLOT, 0xFF, (size_t)T_ * SLOT * 2, stream);

  cast_x_kernel<<<2048, 256, 0, stream>>>(x, xbf);
  pack_w_kernel<<<4096, 256, 0, stream>>>(Wf, Wb, wxT, whT);

  lstm_persist_dp<<<256, 512, 0, stream>>>(whT, wxT, xbf, bfp, bbp, hst, out);
}